// Round 10
// baseline (237.295 us; speedup 1.0000x reference)
//
#include <hip/hip_runtime.h>
#include <math.h>

// Problem constants (fixed by reference: enc (32,64,64,64) fp32, embed (512,64) fp32)
#define DQ 64
#define KQ 512
#define NVEC 131072
#define QOUT_SIZE (NVEC * DQ)              // 8388608
#define LOSS_OFF QOUT_SIZE
#define IDX_OFF (QOUT_SIZE + 1)

#define RPW 32                             // rows per wave (2 MFMA A-tiles)
#define WPB 16                             // waves per block (1024 threads)
#define VPB (RPW * WPB)                    // 512 rows per block
#define NBLK (NVEC / VPB)                  // 256 blocks -> exactly 1 per CU
#define SC 128                             // codes per LDS stage (hi+lo = 32 KB)
#define NST (KQ / SC)                      // 4 stages
#define TIE_THR 0.01f                      // exact rescan when top-2 gap below this (err bound ~1e-3)

typedef __attribute__((ext_vector_type(8))) short short8;          // 8 bf16 = 1 MFMA A/B frag
typedef __attribute__((ext_vector_type(4))) float f32x4;           // MFMA C/D frag

static __device__ __forceinline__ unsigned short f2bf(float f) {   // RNE fp32->bf16
    unsigned u = __float_as_uint(f);
    u += 0x7fff + ((u >> 16) & 1);
    return (unsigned short)(u >> 16);
}
static __device__ __forceinline__ float bf2f(unsigned short h) {
    return __uint_as_float(((unsigned)h) << 16);
}
static __device__ __forceinline__ void cvt8(float4 a, float4 b, short8& hi, short8& lo) {
#define C1(I, V) { unsigned short _h = f2bf(V); hi[I] = (short)_h; lo[I] = (short)f2bf((V) - bf2f(_h)); }
    C1(0, a.x) C1(1, a.y) C1(2, a.z) C1(3, a.w)
    C1(4, b.x) C1(5, b.y) C1(6, b.z) C1(7, b.w)
#undef C1
}

// Init: hi/lo bf16 codebook in XOR-SWIZZLED layout (chunk c of row k stored at
// slot c ^ (k&7)) so the main kernel's ds_read_b128 B-frag reads are uniform
// over banks (8 lanes per bank-quartet = wave64 b128 minimum -> conflict-free),
// while staging stays a verbatim contiguous copy. Plus e_sq and loss zeroing.
__global__ void vq_init_kernel(const float* __restrict__ embed,
                               unsigned short* __restrict__ ehi,
                               unsigned short* __restrict__ elo,
                               float* __restrict__ esq,
                               float* __restrict__ out) {
    const int t = blockIdx.x * 64 + threadIdx.x;   // 0..4095
    if (t == 0) out[LOSS_OFF] = 0.0f;
    const int k = t >> 3;            // codebook row
    const int c = t & 7;             // 16-byte chunk (8 dims)
    const float4* p = (const float4*)(embed + (size_t)k * DQ + c * 8);
    float4 a = p[0], b = p[1];
    short8 hi, lo;
    cvt8(a, b, hi, lo);
    const int slot = c ^ (k & 7);    // XOR swizzle
    *(short8*)(ehi + (size_t)k * DQ + slot * 8) = hi;
    *(short8*)(elo + (size_t)k * DQ + slot * 8) = lo;

    float ps = 0.f;
    ps = fmaf(a.x, a.x, ps); ps = fmaf(a.y, a.y, ps); ps = fmaf(a.z, a.z, ps); ps = fmaf(a.w, a.w, ps);
    ps = fmaf(b.x, b.x, ps); ps = fmaf(b.y, b.y, ps); ps = fmaf(b.z, b.z, ps); ps = fmaf(b.w, b.w, ps);
    ps += __shfl_xor(ps, 1);
    ps += __shfl_xor(ps, 2);
    ps += __shfl_xor(ps, 4);
    if (c == 0) esq[k] = ps;
}

// R6-R9 lesson: any global load in the k-loop -> latency-bound at ~100+ us no
// matter the traffic. This version keeps the k-loop on LDS+MFMA+VALU ONLY:
// codebook staged through LDS in 4 stages of 128 codes; next stage's global
// loads are issued into regs BEFORE compute (no VM op in compute -> no vmcnt
// entanglement -> true overlap). 1024-thr blocks force 16 waves/CU residency
// (R8/R9's one-wave workgroups were capped at ~5/CU by the scheduler).
// R3 lesson: register arrays only indexed by fully-unrolled constants.
// R7 lesson: demand must fit the 128-VGPR cap: ~123 here.
__global__ __launch_bounds__(1024, 4) void vq_mfma_kernel(const float* __restrict__ enc,
                                                          const float* __restrict__ embed,
                                                          const unsigned short* __restrict__ ehi,
                                                          const unsigned short* __restrict__ elo,
                                                          const float* __restrict__ esq,
                                                          float* __restrict__ out) {
    __shared__ unsigned short hs[SC * DQ];   // 16 KB swizzled hi stage
    __shared__ unsigned short ls_[SC * DQ];  // 16 KB swizzled lo stage
    __shared__ float esq_s[KQ];              // 2 KB
    __shared__ int bidx_s[VPB];              // 2 KB
    __shared__ int flag_s[VPB];              // 2 KB

    const int tid = threadIdx.x;
    const int lane = tid & 63;
    const int w = tid >> 6;            // wave 0..15
    const int l15 = lane & 15;
    const int l4 = lane >> 4;          // 0..3
    const int vb = blockIdx.x * VPB + w * RPW;

    if (tid < KQ) esq_s[tid] = esq[tid];

    // A fragments for 2 tiles: row m = l15 (+a*16), k-chunks l4*8 and 32+l4*8.
    short8 ahA[2], alA[2], ahB[2], alB[2];
#pragma unroll
    for (int a = 0; a < 2; a++) {
        const float* base = enc + (size_t)(vb + a * 16 + l15) * DQ + l4 * 8;
        const float4* p0 = (const float4*)base;
        const float4* p1 = (const float4*)(base + 32);
        cvt8(p0[0], p0[1], ahA[a], alA[a]);
        cvt8(p1[0], p1[1], ahB[a], alB[a]);
    }

    float m1[8], m2[8];
    int i1[8];
#pragma unroll
    for (int r = 0; r < 8; r++) { m1[r] = 3.4e38f; m2[r] = 3.4e38f; i1[r] = 0; }

    // Swizzled B-frag slot offsets (elements). key = row&7 = l15&7 (stage base
    // and tile base are multiples of 8 rows).
    const int sl0 = ((l4 ^ (l15 & 7))) * 8;  // chunk l4     (dims l4*8..+8)
    const int sl1 = sl0 ^ 32;                // chunk 4+l4   (dims 32+l4*8..+8)
    const unsigned short* hrow = hs + l15 * DQ;
    const unsigned short* lrow = ls_ + l15 * DQ;

    // Stage-0 prefetch into regs (16 B hi + 16 B lo per thread = full 32 KB stage).
    short8 rh = *(const short8*)(ehi + tid * 8);
    short8 rl = *(const short8*)(elo + tid * 8);

#define LDB(H0, H1, L0, L1, S) { const int _o = (S) * 16 * DQ; \
    H0 = *(const short8*)(hrow + _o + sl0); H1 = *(const short8*)(hrow + _o + sl1); \
    L0 = *(const short8*)(lrow + _o + sl0); L1 = *(const short8*)(lrow + _o + sl1); }

#define BODY(ST, S, BH0, BH1, BL0, BL1) { \
    const int code = (ST) * SC + (S) * 16 + l15; \
    const float ev = esq_s[code]; \
    _Pragma("unroll") \
    for (int a = 0; a < 2; a++) { \
        f32x4 acc = {0.f, 0.f, 0.f, 0.f}; \
        acc = __builtin_amdgcn_mfma_f32_16x16x32_bf16(ahA[a], BH0, acc, 0, 0, 0); \
        acc = __builtin_amdgcn_mfma_f32_16x16x32_bf16(ahB[a], BH1, acc, 0, 0, 0); \
        acc = __builtin_amdgcn_mfma_f32_16x16x32_bf16(alA[a], BH0, acc, 0, 0, 0); \
        acc = __builtin_amdgcn_mfma_f32_16x16x32_bf16(alB[a], BH1, acc, 0, 0, 0); \
        acc = __builtin_amdgcn_mfma_f32_16x16x32_bf16(ahA[a], BL0, acc, 0, 0, 0); \
        acc = __builtin_amdgcn_mfma_f32_16x16x32_bf16(ahB[a], BL1, acc, 0, 0, 0); \
        _Pragma("unroll") \
        for (int r = 0; r < 4; r++) { \
            float v = fmaf(-2.0f, acc[r], ev); \
            bool lt = v < m1[a * 4 + r]; \
            i1[a * 4 + r] = lt ? code : i1[a * 4 + r]; \
            m2[a * 4 + r] = fminf(m2[a * 4 + r], fmaxf(m1[a * 4 + r], v)); \
            m1[a * 4 + r] = fminf(m1[a * 4 + r], v); \
        } \
    } }

    for (int st = 0; st < NST; st++) {
        __syncthreads();                         // prev stage's readers done
        *(short8*)(hs + tid * 8) = rh;           // stride-1 b128 writes: conflict-free
        *(short8*)(ls_ + tid * 8) = rl;
        __syncthreads();                         // stage visible
        if (st < NST - 1) {                      // overlap next stage's loads w/ compute
            rh = *(const short8*)(ehi + (st + 1) * (SC * DQ) + tid * 8);
            rl = *(const short8*)(elo + (st + 1) * (SC * DQ) + tid * 8);
        }
        // 8 tiles, even/odd B double-buffer in regs (pure LDS->MFMA->VALU)
        short8 b0h0, b0h1, b0l0, b0l1, b1h0, b1h1, b1l0, b1l1;
        LDB(b0h0, b0h1, b0l0, b0l1, 0)
#pragma unroll
        for (int s = 0; s < 8; s += 2) {
            LDB(b1h0, b1h1, b1l0, b1l1, s + 1)
            BODY(st, s, b0h0, b0h1, b0l0, b0l1)
            if (s + 2 < 8) LDB(b0h0, b0h1, b0l0, b0l1, s + 2)
            BODY(st, s + 1, b1h0, b1h1, b1l0, b1l1)
        }
    }
#undef LDB
#undef BODY

    // Cross-lane merge over the 16 cols (xor on lane&15 bits).
#pragma unroll
    for (int m = 1; m <= 8; m <<= 1) {
#pragma unroll
        for (int r = 0; r < 8; r++) {
            float o1 = __shfl_xor(m1[r], m);
            float o2 = __shfl_xor(m2[r], m);
            int oi = __shfl_xor(i1[r], m);
            float nm2 = fminf(fminf(m2[r], o2), fmaxf(m1[r], o1));
            bool lt = o1 < m1[r];
            i1[r] = lt ? oi : i1[r];
            m1[r] = fminf(m1[r], o1);
            m2[r] = nm2;
        }
    }

    if (l15 == 0) {
#pragma unroll
        for (int a = 0; a < 2; a++)
#pragma unroll
            for (int r = 0; r < 4; r++) {
                const int row = a * 16 + l4 * 4 + r;
                bidx_s[w * RPW + row] = i1[a * 4 + r];
                flag_s[w * RPW + row] = (m2[a * 4 + r] - m1[a * 4 + r] < TIE_THR) ? 1 : 0;
            }
    }
    // bidx_s/flag_s regions are per-wave -> wave-internal LDS visibility only
    // (lockstep + compiler lgkmcnt); no block barrier needed.

    // Exact fp64 rescan of flagged rows (wave-uniform branch; rare ~1%).
    for (int row = 0; row < RPW; row++) {
        if (flag_s[w * RPW + row]) {
            const int v = vb + row;
            const float4* xe = (const float4*)(enc + (size_t)v * DQ);
            unsigned long long best = ~0ULL;
            for (int q = 0; q < 8; q++) {
                const int c = lane * 8 + q;
                const float4* ee = (const float4*)(embed + (size_t)c * DQ);
                double a = 0.0;
                for (int j = 0; j < 16; j++) {          // global ptrs: runtime j fine
                    float4 xx = xe[j], ez = ee[j];
                    double d0 = (double)xx.x - (double)ez.x; a = fma(d0, d0, a);
                    double d1 = (double)xx.y - (double)ez.y; a = fma(d1, d1, a);
                    double d2 = (double)xx.z - (double)ez.z; a = fma(d2, d2, a);
                    double d3 = (double)xx.w - (double)ez.w; a = fma(d3, d3, a);
                }
                unsigned long long p =
                    (((unsigned long long)__double_as_longlong(a)) & ~511ULL) | (unsigned)c;
                best = (p < best) ? p : best;
            }
#pragma unroll
            for (int mm = 1; mm < 64; mm <<= 1) {
                unsigned long long ob = (unsigned long long)__shfl_xor((long long)best, mm);
                best = (ob < best) ? ob : best;
            }
            if (lane == 0) bidx_s[w * RPW + row] = (int)(best & 511ULL);
        }
    }

    // Epilogue: per tile a, lane handles row a*16+l15, chunks l4*8 and 32+l4*8.
    // x recomputed from the hi/lo frags (≈1e-5 rel err; loss-only).
    float lsum = 0.f;
#pragma unroll
    for (int a = 0; a < 2; a++) {
        const int myv = vb + a * 16 + l15;
        const int qb = bidx_s[w * RPW + a * 16 + l15];
        const float* qbase = embed + (size_t)qb * DQ + l4 * 8;
        const float4* qa = (const float4*)qbase;
        const float4* qc = (const float4*)(qbase + 32);
        float4 q0 = qa[0], q1 = qa[1], q2 = qc[0], q3 = qc[1];
        float* obase = out + (size_t)myv * DQ + l4 * 8;
        ((float4*)obase)[0] = q0; ((float4*)obase)[1] = q1;
        ((float4*)(obase + 32))[0] = q2; ((float4*)(obase + 32))[1] = q3;
        if (l4 == 0) out[IDX_OFF + myv] = (float)qb;

        float d;
        d = q0.x - (bf2f(ahA[a][0]) + bf2f(alA[a][0])); lsum = fmaf(d, d, lsum);
        d = q0.y - (bf2f(ahA[a][1]) + bf2f(alA[a][1])); lsum = fmaf(d, d, lsum);
        d = q0.z - (bf2f(ahA[a][2]) + bf2f(alA[a][2])); lsum = fmaf(d, d, lsum);
        d = q0.w - (bf2f(ahA[a][3]) + bf2f(alA[a][3])); lsum = fmaf(d, d, lsum);
        d = q1.x - (bf2f(ahA[a][4]) + bf2f(alA[a][4])); lsum = fmaf(d, d, lsum);
        d = q1.y - (bf2f(ahA[a][5]) + bf2f(alA[a][5])); lsum = fmaf(d, d, lsum);
        d = q1.z - (bf2f(ahA[a][6]) + bf2f(alA[a][6])); lsum = fmaf(d, d, lsum);
        d = q1.w - (bf2f(ahA[a][7]) + bf2f(alA[a][7])); lsum = fmaf(d, d, lsum);
        d = q2.x - (bf2f(ahB[a][0]) + bf2f(alB[a][0])); lsum = fmaf(d, d, lsum);
        d = q2.y - (bf2f(ahB[a][1]) + bf2f(alB[a][1])); lsum = fmaf(d, d, lsum);
        d = q2.z - (bf2f(ahB[a][2]) + bf2f(alB[a][2])); lsum = fmaf(d, d, lsum);
        d = q2.w - (bf2f(ahB[a][3]) + bf2f(alB[a][3])); lsum = fmaf(d, d, lsum);
        d = q3.x - (bf2f(ahB[a][4]) + bf2f(alB[a][4])); lsum = fmaf(d, d, lsum);
        d = q3.y - (bf2f(ahB[a][5]) + bf2f(alB[a][5])); lsum = fmaf(d, d, lsum);
        d = q3.z - (bf2f(ahB[a][6]) + bf2f(alB[a][6])); lsum = fmaf(d, d, lsum);
        d = q3.w - (bf2f(ahB[a][7]) + bf2f(alB[a][7])); lsum = fmaf(d, d, lsum);
    }

#pragma unroll
    for (int off = 32; off > 0; off >>= 1) lsum += __shfl_down(lsum, off);
    if (lane == 0) atomicAdd(out + LOSS_OFF, lsum * (2.0f / (float)QOUT_SIZE));
}

extern "C" void kernel_launch(void* const* d_in, const int* in_sizes, int n_in,
                              void* d_out, int out_size, void* d_ws, size_t ws_size,
                              hipStream_t stream) {
    const float* enc = (const float*)d_in[0];
    const float* embed = (const float*)d_in[1];
    float* out = (float*)d_out;
    // ws layout: ehi[512*64] u16 | elo[512*64] u16 | esq[512] f32  (~130 KB)
    unsigned short* ehi = (unsigned short*)d_ws;
    unsigned short* elo = ehi + KQ * DQ;
    float* esq = (float*)(elo + KQ * DQ);

    hipLaunchKernelGGL(vq_init_kernel, dim3(64), dim3(64), 0, stream,
                       embed, ehi, elo, esq, out);
    hipLaunchKernelGGL(vq_mfma_kernel, dim3(NBLK), dim3(1024), 0, stream,
                       enc, embed, ehi, elo, esq, out);
}

// Round 11
// 236.522 us; speedup vs baseline: 1.0033x; 1.0033x over previous
//
#include <hip/hip_runtime.h>
#include <math.h>

// Problem constants (fixed by reference: enc (32,64,64,64) fp32, embed (512,64) fp32)
#define DQ 64
#define KQ 512
#define NVEC 131072
#define QOUT_SIZE (NVEC * DQ)              // 8388608
#define LOSS_OFF QOUT_SIZE
#define IDX_OFF (QOUT_SIZE + 1)

#define RPW 32                             // rows per wave (2 MFMA A-tiles)
#define WPB 16                             // waves per block (1024 threads)
#define VPB (RPW * WPB)                    // 512 rows per block
#define NBLK (NVEC / VPB)                  // 256 blocks -> exactly 1 per CU
#define SC 128                             // codes per LDS stage (hi+lo = 32 KB)
#define NST (KQ / SC)                      // 4 stages
#define TIE_THR 0.01f                      // exact rescan when top-2 gap below this (err bound ~1e-3)

typedef __attribute__((ext_vector_type(8))) short short8;          // 8 bf16 = 1 MFMA A/B frag
typedef __attribute__((ext_vector_type(4))) float f32x4;           // MFMA C/D frag

static __device__ __forceinline__ unsigned short f2bf(float f) {   // RNE fp32->bf16
    unsigned u = __float_as_uint(f);
    u += 0x7fff + ((u >> 16) & 1);
    return (unsigned short)(u >> 16);
}
static __device__ __forceinline__ float bf2f(unsigned short h) {
    return __uint_as_float(((unsigned)h) << 16);
}
static __device__ __forceinline__ void cvt8(float4 a, float4 b, short8& hi, short8& lo) {
#define C1(I, V) { unsigned short _h = f2bf(V); hi[I] = (short)_h; lo[I] = (short)f2bf((V) - bf2f(_h)); }
    C1(0, a.x) C1(1, a.y) C1(2, a.z) C1(3, a.w)
    C1(4, b.x) C1(5, b.y) C1(6, b.z) C1(7, b.w)
#undef C1
}

// Init: hi/lo bf16 codebook in XOR-SWIZZLED layout (chunk c of row k stored at
// slot c ^ (k&7)) so the main kernel's ds_read_b128 B-frag reads are uniform
// over banks, while staging stays a verbatim contiguous copy. Plus e_sq + loss=0.
__global__ void vq_init_kernel(const float* __restrict__ embed,
                               unsigned short* __restrict__ ehi,
                               unsigned short* __restrict__ elo,
                               float* __restrict__ esq,
                               float* __restrict__ out) {
    const int t = blockIdx.x * 64 + threadIdx.x;   // 0..4095
    if (t == 0) out[LOSS_OFF] = 0.0f;
    const int k = t >> 3;            // codebook row
    const int c = t & 7;             // 16-byte chunk (8 dims)
    const float4* p = (const float4*)(embed + (size_t)k * DQ + c * 8);
    float4 a = p[0], b = p[1];
    short8 hi, lo;
    cvt8(a, b, hi, lo);
    const int slot = c ^ (k & 7);    // XOR swizzle
    *(short8*)(ehi + (size_t)k * DQ + slot * 8) = hi;
    *(short8*)(elo + (size_t)k * DQ + slot * 8) = lo;

    float ps = 0.f;
    ps = fmaf(a.x, a.x, ps); ps = fmaf(a.y, a.y, ps); ps = fmaf(a.z, a.z, ps); ps = fmaf(a.w, a.w, ps);
    ps = fmaf(b.x, b.x, ps); ps = fmaf(b.y, b.y, ps); ps = fmaf(b.z, b.z, ps); ps = fmaf(b.w, b.w, ps);
    ps += __shfl_xor(ps, 1);
    ps += __shfl_xor(ps, 2);
    ps += __shfl_xor(ps, 4);
    if (c == 0) esq[k] = ps;
}

// R7-R10 lesson (the allocator mystery): HIP __launch_bounds__(B, w) sets only
// the MIN of amdgpu-waves-per-eu; the max stays 8, and the scheduler squeezes
// register pressure toward the MAX, spilling to reach it (R10: chose 64 VGPRs
// + 250 MB spill traffic when the cap allowed 128). Fix: pin BOTH bounds with
// amdgpu_waves_per_eu(4,4) -> target exactly 4 waves/EU -> 128-VGPR budget,
// demand ~110 fits, no spill.
// R6-R9 lesson: no global loads in the k-loop (latency-bound otherwise) —
// codebook staged through LDS in 4 stages; next stage's global loads issued
// into regs BEFORE compute; compute touches LDS+MFMA+VALU only.
// R3 lesson: register arrays only indexed by fully-unrolled constants.
__global__ __attribute__((amdgpu_flat_work_group_size(1024, 1024),
                          amdgpu_waves_per_eu(4, 4)))
void vq_mfma_kernel(const float* __restrict__ enc,
                    const float* __restrict__ embed,
                    const unsigned short* __restrict__ ehi,
                    const unsigned short* __restrict__ elo,
                    const float* __restrict__ esq,
                    float* __restrict__ out) {
    __shared__ unsigned short hs[SC * DQ];   // 16 KB swizzled hi stage
    __shared__ unsigned short ls_[SC * DQ];  // 16 KB swizzled lo stage
    __shared__ float esq_s[KQ];              // 2 KB
    __shared__ int bidx_s[VPB];              // 2 KB
    __shared__ int flag_s[VPB];              // 2 KB

    const int tid = threadIdx.x;
    const int lane = tid & 63;
    const int w = tid >> 6;            // wave 0..15
    const int l15 = lane & 15;
    const int l4 = lane >> 4;          // 0..3
    const int vb = blockIdx.x * VPB + w * RPW;

    if (tid < KQ) esq_s[tid] = esq[tid];

    // A fragments for 2 tiles: row m = l15 (+a*16), k-chunks l4*8 and 32+l4*8.
    short8 ahA[2], alA[2], ahB[2], alB[2];
#pragma unroll
    for (int a = 0; a < 2; a++) {
        const float* base = enc + (size_t)(vb + a * 16 + l15) * DQ + l4 * 8;
        const float4* p0 = (const float4*)base;
        const float4* p1 = (const float4*)(base + 32);
        cvt8(p0[0], p0[1], ahA[a], alA[a]);
        cvt8(p1[0], p1[1], ahB[a], alB[a]);
    }

    float m1[8], m2[8];
    int i1[8];
#pragma unroll
    for (int r = 0; r < 8; r++) { m1[r] = 3.4e38f; m2[r] = 3.4e38f; i1[r] = 0; }

    // Swizzled B-frag slot offsets (elements). key = row&7 = l15&7 (stage base
    // and tile base are multiples of 8 rows).
    const int sl0 = ((l4 ^ (l15 & 7))) * 8;  // chunk l4     (dims l4*8..+8)
    const int sl1 = sl0 ^ 32;                // chunk 4+l4   (dims 32+l4*8..+8)
    const unsigned short* hrow = hs + l15 * DQ;
    const unsigned short* lrow = ls_ + l15 * DQ;

    // Stage-0 prefetch into regs (16 B hi + 16 B lo per thread = full 32 KB stage).
    short8 rh = *(const short8*)(ehi + tid * 8);
    short8 rl = *(const short8*)(elo + tid * 8);

#define LDB(H0, H1, L0, L1, S) { const int _o = (S) * 16 * DQ; \
    H0 = *(const short8*)(hrow + _o + sl0); H1 = *(const short8*)(hrow + _o + sl1); \
    L0 = *(const short8*)(lrow + _o + sl0); L1 = *(const short8*)(lrow + _o + sl1); }

#define BODY(ST, S, BH0, BH1, BL0, BL1) { \
    const int code = (ST) * SC + (S) * 16 + l15; \
    const float ev = esq_s[code]; \
    _Pragma("unroll") \
    for (int a = 0; a < 2; a++) { \
        f32x4 acc = {0.f, 0.f, 0.f, 0.f}; \
        acc = __builtin_amdgcn_mfma_f32_16x16x32_bf16(ahA[a], BH0, acc, 0, 0, 0); \
        acc = __builtin_amdgcn_mfma_f32_16x16x32_bf16(ahB[a], BH1, acc, 0, 0, 0); \
        acc = __builtin_amdgcn_mfma_f32_16x16x32_bf16(alA[a], BH0, acc, 0, 0, 0); \
        acc = __builtin_amdgcn_mfma_f32_16x16x32_bf16(alB[a], BH1, acc, 0, 0, 0); \
        acc = __builtin_amdgcn_mfma_f32_16x16x32_bf16(ahA[a], BL0, acc, 0, 0, 0); \
        acc = __builtin_amdgcn_mfma_f32_16x16x32_bf16(ahB[a], BL1, acc, 0, 0, 0); \
        _Pragma("unroll") \
        for (int r = 0; r < 4; r++) { \
            float v = fmaf(-2.0f, acc[r], ev); \
            bool lt = v < m1[a * 4 + r]; \
            i1[a * 4 + r] = lt ? code : i1[a * 4 + r]; \
            m2[a * 4 + r] = fminf(m2[a * 4 + r], fmaxf(m1[a * 4 + r], v)); \
            m1[a * 4 + r] = fminf(m1[a * 4 + r], v); \
        } \
    } }

    for (int st = 0; st < NST; st++) {
        __syncthreads();                         // prev stage's readers done
        *(short8*)(hs + tid * 8) = rh;           // stride-1 b128 writes: conflict-free
        *(short8*)(ls_ + tid * 8) = rl;
        __syncthreads();                         // stage visible
        if (st < NST - 1) {                      // overlap next stage's loads w/ compute
            rh = *(const short8*)(ehi + (st + 1) * (SC * DQ) + tid * 8);
            rl = *(const short8*)(elo + (st + 1) * (SC * DQ) + tid * 8);
        }
        // 8 tiles, even/odd B double-buffer in regs (pure LDS->MFMA->VALU)
        short8 b0h0, b0h1, b0l0, b0l1, b1h0, b1h1, b1l0, b1l1;
        LDB(b0h0, b0h1, b0l0, b0l1, 0)
#pragma unroll
        for (int s = 0; s < 8; s += 2) {
            LDB(b1h0, b1h1, b1l0, b1l1, s + 1)
            BODY(st, s, b0h0, b0h1, b0l0, b0l1)
            if (s + 2 < 8) LDB(b0h0, b0h1, b0l0, b0l1, s + 2)
            BODY(st, s + 1, b1h0, b1h1, b1l0, b1l1)
        }
    }
#undef LDB
#undef BODY

    // Cross-lane merge over the 16 cols (xor on lane&15 bits).
#pragma unroll
    for (int m = 1; m <= 8; m <<= 1) {
#pragma unroll
        for (int r = 0; r < 8; r++) {
            float o1 = __shfl_xor(m1[r], m);
            float o2 = __shfl_xor(m2[r], m);
            int oi = __shfl_xor(i1[r], m);
            float nm2 = fminf(fminf(m2[r], o2), fmaxf(m1[r], o1));
            bool lt = o1 < m1[r];
            i1[r] = lt ? oi : i1[r];
            m1[r] = fminf(m1[r], o1);
            m2[r] = nm2;
        }
    }

    if (l15 == 0) {
#pragma unroll
        for (int a = 0; a < 2; a++)
#pragma unroll
            for (int r = 0; r < 4; r++) {
                const int row = a * 16 + l4 * 4 + r;
                bidx_s[w * RPW + row] = i1[a * 4 + r];
                flag_s[w * RPW + row] = (m2[a * 4 + r] - m1[a * 4 + r] < TIE_THR) ? 1 : 0;
            }
    }
    // bidx_s/flag_s regions are per-wave -> wave-internal LDS visibility only.

    // Exact fp64 rescan of flagged rows (wave-uniform branch; rare ~1%).
    for (int row = 0; row < RPW; row++) {
        if (flag_s[w * RPW + row]) {
            const int v = vb + row;
            const float4* xe = (const float4*)(enc + (size_t)v * DQ);
            unsigned long long best = ~0ULL;
            for (int q = 0; q < 8; q++) {
                const int c = lane * 8 + q;
                const float4* ee = (const float4*)(embed + (size_t)c * DQ);
                double a = 0.0;
                for (int j = 0; j < 16; j++) {          // global ptrs: runtime j fine
                    float4 xx = xe[j], ez = ee[j];
                    double d0 = (double)xx.x - (double)ez.x; a = fma(d0, d0, a);
                    double d1 = (double)xx.y - (double)ez.y; a = fma(d1, d1, a);
                    double d2 = (double)xx.z - (double)ez.z; a = fma(d2, d2, a);
                    double d3 = (double)xx.w - (double)ez.w; a = fma(d3, d3, a);
                }
                unsigned long long p =
                    (((unsigned long long)__double_as_longlong(a)) & ~511ULL) | (unsigned)c;
                best = (p < best) ? p : best;
            }
#pragma unroll
            for (int mm = 1; mm < 64; mm <<= 1) {
                unsigned long long ob = (unsigned long long)__shfl_xor((long long)best, mm);
                best = (ob < best) ? ob : best;
            }
            if (lane == 0) bidx_s[w * RPW + row] = (int)(best & 511ULL);
        }
    }

    // Epilogue: per tile a, lane handles row a*16+l15, chunks l4*8 and 32+l4*8.
    // x recomputed from the hi/lo frags (≈1e-5 rel err; loss-only).
    float lsum = 0.f;
#pragma unroll
    for (int a = 0; a < 2; a++) {
        const int myv = vb + a * 16 + l15;
        const int qb = bidx_s[w * RPW + a * 16 + l15];
        const float* qbase = embed + (size_t)qb * DQ + l4 * 8;
        const float4* qa = (const float4*)qbase;
        const float4* qc = (const float4*)(qbase + 32);
        float4 q0 = qa[0], q1 = qa[1], q2 = qc[0], q3 = qc[1];
        float* obase = out + (size_t)myv * DQ + l4 * 8;
        ((float4*)obase)[0] = q0; ((float4*)obase)[1] = q1;
        ((float4*)(obase + 32))[0] = q2; ((float4*)(obase + 32))[1] = q3;
        if (l4 == 0) out[IDX_OFF + myv] = (float)qb;

        float d;
        d = q0.x - (bf2f(ahA[a][0]) + bf2f(alA[a][0])); lsum = fmaf(d, d, lsum);
        d = q0.y - (bf2f(ahA[a][1]) + bf2f(alA[a][1])); lsum = fmaf(d, d, lsum);
        d = q0.z - (bf2f(ahA[a][2]) + bf2f(alA[a][2])); lsum = fmaf(d, d, lsum);
        d = q0.w - (bf2f(ahA[a][3]) + bf2f(alA[a][3])); lsum = fmaf(d, d, lsum);
        d = q1.x - (bf2f(ahA[a][4]) + bf2f(alA[a][4])); lsum = fmaf(d, d, lsum);
        d = q1.y - (bf2f(ahA[a][5]) + bf2f(alA[a][5])); lsum = fmaf(d, d, lsum);
        d = q1.z - (bf2f(ahA[a][6]) + bf2f(alA[a][6])); lsum = fmaf(d, d, lsum);
        d = q1.w - (bf2f(ahA[a][7]) + bf2f(alA[a][7])); lsum = fmaf(d, d, lsum);
        d = q2.x - (bf2f(ahB[a][0]) + bf2f(alB[a][0])); lsum = fmaf(d, d, lsum);
        d = q2.y - (bf2f(ahB[a][1]) + bf2f(alB[a][1])); lsum = fmaf(d, d, lsum);
        d = q2.z - (bf2f(ahB[a][2]) + bf2f(alB[a][2])); lsum = fmaf(d, d, lsum);
        d = q2.w - (bf2f(ahB[a][3]) + bf2f(alB[a][3])); lsum = fmaf(d, d, lsum);
        d = q3.x - (bf2f(ahB[a][4]) + bf2f(alB[a][4])); lsum = fmaf(d, d, lsum);
        d = q3.y - (bf2f(ahB[a][5]) + bf2f(alB[a][5])); lsum = fmaf(d, d, lsum);
        d = q3.z - (bf2f(ahB[a][6]) + bf2f(alB[a][6])); lsum = fmaf(d, d, lsum);
        d = q3.w - (bf2f(ahB[a][7]) + bf2f(alB[a][7])); lsum = fmaf(d, d, lsum);
    }

#pragma unroll
    for (int off = 32; off > 0; off >>= 1) lsum += __shfl_down(lsum, off);
    if (lane == 0) atomicAdd(out + LOSS_OFF, lsum * (2.0f / (float)QOUT_SIZE));
}

extern "C" void kernel_launch(void* const* d_in, const int* in_sizes, int n_in,
                              void* d_out, int out_size, void* d_ws, size_t ws_size,
                              hipStream_t stream) {
    const float* enc = (const float*)d_in[0];
    const float* embed = (const float*)d_in[1];
    float* out = (float*)d_out;
    // ws layout: ehi[512*64] u16 | elo[512*64] u16 | esq[512] f32  (~130 KB)
    unsigned short* ehi = (unsigned short*)d_ws;
    unsigned short* elo = ehi + KQ * DQ;
    float* esq = (float*)(elo + KQ * DQ);

    hipLaunchKernelGGL(vq_init_kernel, dim3(64), dim3(64), 0, stream,
                       embed, ehi, elo, esq, out);
    hipLaunchKernelGGL(vq_mfma_kernel, dim3(NBLK), dim3(1024), 0, stream,
                       enc, embed, ehi, elo, esq, out);
}

// Round 12
// 170.903 us; speedup vs baseline: 1.3885x; 1.3839x over previous
//
#include <hip/hip_runtime.h>
#include <math.h>

// Problem constants (fixed by reference: enc (32,64,64,64) fp32, embed (512,64) fp32)
#define DQ 64
#define KQ 512
#define NVEC 131072
#define QOUT_SIZE (NVEC * DQ)              // 8388608
#define LOSS_OFF QOUT_SIZE
#define IDX_OFF (QOUT_SIZE + 1)

#define RPW 64                             // rows per wave (4 MFMA A-tiles)
#define WPB 4                              // waves per block (256 threads)
#define VPB (RPW * WPB)                    // 256 rows per block
#define NBLK (NVEC / VPB)                  // 512 blocks -> 2 per CU
#define SC 64                              // codes per LDS stage
#define NST (KQ / SC)                      // 8 stages
#define SDQ (SC * DQ)                      // 4096 shorts per stage buffer
#define PADS 2400                          // pad shorts per stage buffer (see below)
#define SDQ_P (SDQ + PADS)                 // padded buffer stride
#define TIE_THR 0.01f                      // exact rescan when top-2 gap below this (err bound ~3e-4)

typedef __attribute__((ext_vector_type(8))) short short8;          // 8 bf16 = 1 MFMA A/B frag
typedef __attribute__((ext_vector_type(4))) float f32x4;           // MFMA C/D frag

static __device__ __forceinline__ unsigned short f2bf(float f) {   // RNE fp32->bf16
    unsigned u = __float_as_uint(f);
    u += 0x7fff + ((u >> 16) & 1);
    return (unsigned short)(u >> 16);
}
static __device__ __forceinline__ float bf2f(unsigned short h) {
    return __uint_as_float(((unsigned)h) << 16);
}
static __device__ __forceinline__ void cvt8(float4 a, float4 b, short8& hi, short8& lo) {
#define C1(I, V) { unsigned short _h = f2bf(V); hi[I] = (short)_h; lo[I] = (short)f2bf((V) - bf2f(_h)); }
    C1(0, a.x) C1(1, a.y) C1(2, a.z) C1(3, a.w)
    C1(4, b.x) C1(5, b.y) C1(6, b.z) C1(7, b.w)
#undef C1
}

// Init: hi/lo bf16 codebook in XOR-SWIZZLED layout (chunk c of row k stored at
// slot c ^ (k&7)) so main-kernel ds_read_b128 B-frag reads are 2-way max
// (free), while staging stays a verbatim contiguous copy. Plus e_sq + loss=0.
__global__ void vq_init_kernel(const float* __restrict__ embed,
                               unsigned short* __restrict__ ehi,
                               unsigned short* __restrict__ elo,
                               float* __restrict__ esq,
                               float* __restrict__ out) {
    const int t = blockIdx.x * 64 + threadIdx.x;   // 0..4095
    if (t == 0) out[LOSS_OFF] = 0.0f;
    const int k = t >> 3;            // codebook row
    const int c = t & 7;             // 16-byte chunk (8 dims)
    const float4* p = (const float4*)(embed + (size_t)k * DQ + c * 8);
    float4 a = p[0], b = p[1];
    short8 hi, lo;
    cvt8(a, b, hi, lo);
    const int slot = c ^ (k & 7);    // XOR swizzle
    *(short8*)(ehi + (size_t)k * DQ + slot * 8) = hi;
    *(short8*)(elo + (size_t)k * DQ + slot * 8) = lo;

    float ps = 0.f;
    ps = fmaf(a.x, a.x, ps); ps = fmaf(a.y, a.y, ps); ps = fmaf(a.z, a.z, ps); ps = fmaf(a.w, a.w, ps);
    ps = fmaf(b.x, b.x, ps); ps = fmaf(b.y, b.y, ps); ps = fmaf(b.z, b.z, ps); ps = fmaf(b.w, b.w, ps);
    ps += __shfl_xor(ps, 1);
    ps += __shfl_xor(ps, 2);
    ps += __shfl_xor(ps, 4);
    if (c == 0) esq[k] = ps;
}

// R7-R11 lesson (allocator, final theory): the backend sets its VGPR budget
// from occupancy limits it can PROVE from launch constraints. Attributes
// (launch_bounds min-waves, waves_per_eu) were all ignored; LDS per WG is a
// hard constraint it does respect. So: 256-thr WGs + 55 KB LDS -> max
// 2 WGs/CU (160/55) -> 2 waves/SIMD -> 256-VGPR budget -> demand ~200 fits,
// no spill. The pad lives as stage-buffer tails (runtime-indexed, can't be
// shrunk by the compiler).
// R6-R9 lesson: no global loads in the k-loop. Codebook staged through LDS
// (double-buffered) with reg-prefetch TWO stages ahead: the barrier only ever
// drains loads that already had a full stage of compute to complete.
// R3 lesson: VGPR arrays only indexed by fully-unrolled constants.
__global__ __launch_bounds__(256) void vq_mfma_kernel(const float* __restrict__ enc,
                                                      const float* __restrict__ embed,
                                                      const unsigned short* __restrict__ ehi,
                                                      const unsigned short* __restrict__ elo,
                                                      const float* __restrict__ esq,
                                                      float* __restrict__ out) {
    __shared__ unsigned short hs[2 * SDQ_P];   // hi stages (dbuf, padded): 25.4 KB
    __shared__ unsigned short ls_[2 * SDQ_P];  // lo stages (dbuf, padded): 25.4 KB
    __shared__ float esq_s[KQ];                // 2 KB
    __shared__ int bidx_s[VPB];                // 1 KB
    __shared__ int flag_s[VPB];                // 1 KB
    __shared__ float red[WPB];

    const int tid = threadIdx.x;
    const int lane = tid & 63;
    const int w = tid >> 6;            // wave 0..3
    const int l15 = lane & 15;
    const int l4 = lane >> 4;          // 0..3
    const int vb = blockIdx.x * VPB + w * RPW;

    esq_s[tid] = esq[tid];
    esq_s[tid + 256] = esq[tid + 256];

    // A fragments for 4 tiles: row m = l15 (+a*16), k-chunks l4*8 and 32+l4*8.
    short8 ahA[4], alA[4], ahB[4], alB[4];
#pragma unroll
    for (int a = 0; a < 4; a++) {
        const float* base = enc + (size_t)(vb + a * 16 + l15) * DQ + l4 * 8;
        const float4* p0 = (const float4*)base;
        const float4* p1 = (const float4*)(base + 32);
        cvt8(p0[0], p0[1], ahA[a], alA[a]);
        cvt8(p1[0], p1[1], ahB[a], alB[a]);
    }

    float m1[16], m2[16];
    int i1[16];
#pragma unroll
    for (int r = 0; r < 16; r++) { m1[r] = 3.4e38f; m2[r] = 3.4e38f; i1[r] = 0; }

    // Swizzled B-frag slot offsets (elements); key = l15&7.
    const int sl0 = (l4 ^ (l15 & 7)) * 8;    // chunk l4     (dims l4*8..+8)
    const int sl1 = sl0 ^ 32;                // chunk 4+l4   (dims 32+l4*8..+8)

    // Staging: thread stages 32 B of hi + 32 B of lo per stage, as two b128
    // writes at tid*16B and 4KB+tid*16B (each write: consecutive 16B groups
    // -> 2-way max = free).
    short8 rh0 = *(const short8*)(ehi + tid * 8);
    short8 rh1 = *(const short8*)(ehi + 2048 + tid * 8);
    short8 rl0 = *(const short8*)(elo + tid * 8);
    short8 rl1 = *(const short8*)(elo + 2048 + tid * 8);
    // write stage 0 into buf 0
    *(short8*)(hs + tid * 8) = rh0;  *(short8*)(hs + 2048 + tid * 8) = rh1;
    *(short8*)(ls_ + tid * 8) = rl0; *(short8*)(ls_ + 2048 + tid * 8) = rl1;
    // prefetch stage 1 into regs
    rh0 = *(const short8*)(ehi + SDQ + tid * 8);
    rh1 = *(const short8*)(ehi + SDQ + 2048 + tid * 8);
    rl0 = *(const short8*)(elo + SDQ + tid * 8);
    rl1 = *(const short8*)(elo + SDQ + 2048 + tid * 8);

#define LDB(H0, H1, L0, L1, S) { const int _o = ((S) * 16 + l15) * DQ; \
    H0 = *(const short8*)(hb + _o + sl0); H1 = *(const short8*)(hb + _o + sl1); \
    L0 = *(const short8*)(lb + _o + sl0); L1 = *(const short8*)(lb + _o + sl1); }

#define BODY(ST, S, BH0, BH1, BL0, BL1) { \
    const int code = (ST) * SC + (S) * 16 + l15; \
    const float ev = esq_s[code]; \
    _Pragma("unroll") \
    for (int a = 0; a < 4; a++) { \
        f32x4 acc = {0.f, 0.f, 0.f, 0.f}; \
        acc = __builtin_amdgcn_mfma_f32_16x16x32_bf16(ahA[a], BH0, acc, 0, 0, 0); \
        acc = __builtin_amdgcn_mfma_f32_16x16x32_bf16(ahB[a], BH1, acc, 0, 0, 0); \
        acc = __builtin_amdgcn_mfma_f32_16x16x32_bf16(alA[a], BH0, acc, 0, 0, 0); \
        acc = __builtin_amdgcn_mfma_f32_16x16x32_bf16(alB[a], BH1, acc, 0, 0, 0); \
        acc = __builtin_amdgcn_mfma_f32_16x16x32_bf16(ahA[a], BL0, acc, 0, 0, 0); \
        acc = __builtin_amdgcn_mfma_f32_16x16x32_bf16(ahB[a], BL1, acc, 0, 0, 0); \
        _Pragma("unroll") \
        for (int r = 0; r < 4; r++) { \
            float v = fmaf(-2.0f, acc[r], ev); \
            bool lt = v < m1[a * 4 + r]; \
            i1[a * 4 + r] = lt ? code : i1[a * 4 + r]; \
            m2[a * 4 + r] = fminf(m2[a * 4 + r], fmaxf(m1[a * 4 + r], v)); \
            m1[a * 4 + r] = fminf(m1[a * 4 + r], v); \
        } \
    } }

    for (int st = 0; st < NST; st++) {
        // Drains: LDS writes of buf[st&1] (done last iter) + global loads
        // issued last iter (they had a full stage of compute cover).
        __syncthreads();
        if (st < NST - 1) {                  // write stage st+1 into other buf
            unsigned short* hw = hs + ((st + 1) & 1) * SDQ_P;
            unsigned short* lw = ls_ + ((st + 1) & 1) * SDQ_P;
            *(short8*)(hw + tid * 8) = rh0;  *(short8*)(hw + 2048 + tid * 8) = rh1;
            *(short8*)(lw + tid * 8) = rl0;  *(short8*)(lw + 2048 + tid * 8) = rl1;
        }
        if (st < NST - 2) {                  // prefetch stage st+2 (overlaps compute)
            const int o = (st + 2) * SDQ;
            rh0 = *(const short8*)(ehi + o + tid * 8);
            rh1 = *(const short8*)(ehi + o + 2048 + tid * 8);
            rl0 = *(const short8*)(elo + o + tid * 8);
            rl1 = *(const short8*)(elo + o + 2048 + tid * 8);
        }
        const unsigned short* hb = hs + (st & 1) * SDQ_P;
        const unsigned short* lb = ls_ + (st & 1) * SDQ_P;
        // 4 tiles, even/odd B double-buffer in regs (pure LDS->MFMA->VALU)
        short8 b0h0, b0h1, b0l0, b0l1, b1h0, b1h1, b1l0, b1l1;
        LDB(b0h0, b0h1, b0l0, b0l1, 0)
        LDB(b1h0, b1h1, b1l0, b1l1, 1)
        BODY(st, 0, b0h0, b0h1, b0l0, b0l1)
        LDB(b0h0, b0h1, b0l0, b0l1, 2)
        BODY(st, 1, b1h0, b1h1, b1l0, b1l1)
        LDB(b1h0, b1h1, b1l0, b1l1, 3)
        BODY(st, 2, b0h0, b0h1, b0l0, b0l1)
        BODY(st, 3, b1h0, b1h1, b1l0, b1l1)
    }
#undef LDB
#undef BODY

    // Cross-lane merge over the 16 cols (xor on lane&15 bits).
#pragma unroll
    for (int m = 1; m <= 8; m <<= 1) {
#pragma unroll
        for (int r = 0; r < 16; r++) {
            float o1 = __shfl_xor(m1[r], m);
            float o2 = __shfl_xor(m2[r], m);
            int oi = __shfl_xor(i1[r], m);
            float nm2 = fminf(fminf(m2[r], o2), fmaxf(m1[r], o1));
            bool lt = o1 < m1[r];
            i1[r] = lt ? oi : i1[r];
            m1[r] = fminf(m1[r], o1);
            m2[r] = nm2;
        }
    }

    if (l15 == 0) {
#pragma unroll
        for (int a = 0; a < 4; a++)
#pragma unroll
            for (int r = 0; r < 4; r++) {
                const int row = a * 16 + l4 * 4 + r;
                bidx_s[w * RPW + row] = i1[a * 4 + r];
                flag_s[w * RPW + row] = (m2[a * 4 + r] - m1[a * 4 + r] < TIE_THR) ? 1 : 0;
            }
    }
    // bidx_s/flag_s are per-wave segments -> wave-internal visibility only.

    // Exact fp64 rescan of flagged rows (wave-uniform branch; rare ~1%).
    for (int row = 0; row < RPW; row++) {
        if (flag_s[w * RPW + row]) {
            const int v = vb + row;
            const float4* xe = (const float4*)(enc + (size_t)v * DQ);
            unsigned long long best = ~0ULL;
            for (int q = 0; q < 8; q++) {
                const int c = lane * 8 + q;
                const float4* ee = (const float4*)(embed + (size_t)c * DQ);
                double a = 0.0;
                for (int j = 0; j < 16; j++) {          // global ptrs: runtime j fine
                    float4 xx = xe[j], ez = ee[j];
                    double d0 = (double)xx.x - (double)ez.x; a = fma(d0, d0, a);
                    double d1 = (double)xx.y - (double)ez.y; a = fma(d1, d1, a);
                    double d2 = (double)xx.z - (double)ez.z; a = fma(d2, d2, a);
                    double d3 = (double)xx.w - (double)ez.w; a = fma(d3, d3, a);
                }
                unsigned long long p =
                    (((unsigned long long)__double_as_longlong(a)) & ~511ULL) | (unsigned)c;
                best = (p < best) ? p : best;
            }
#pragma unroll
            for (int mm = 1; mm < 64; mm <<= 1) {
                unsigned long long ob = (unsigned long long)__shfl_xor((long long)best, mm);
                best = (ob < best) ? ob : best;
            }
            if (lane == 0) bidx_s[w * RPW + row] = (int)(best & 511ULL);
        }
    }

    // Epilogue: per tile a, lane handles row a*16+l15, chunks l4*8 and 32+l4*8.
    // x recomputed from the hi/lo frags (≈1e-5 rel err; loss-only).
    float lsum = 0.f;
#pragma unroll
    for (int a = 0; a < 4; a++) {
        const int myv = vb + a * 16 + l15;
        const int qb = bidx_s[w * RPW + a * 16 + l15];
        const float* qbase = embed + (size_t)qb * DQ + l4 * 8;
        const float4* qa = (const float4*)qbase;
        const float4* qc = (const float4*)(qbase + 32);
        float4 q0 = qa[0], q1 = qa[1], q2 = qc[0], q3 = qc[1];
        float* obase = out + (size_t)myv * DQ + l4 * 8;
        ((float4*)obase)[0] = q0; ((float4*)obase)[1] = q1;
        ((float4*)(obase + 32))[0] = q2; ((float4*)(obase + 32))[1] = q3;
        if (l4 == 0) out[IDX_OFF + myv] = (float)qb;

        float d;
        d = q0.x - (bf2f(ahA[a][0]) + bf2f(alA[a][0])); lsum = fmaf(d, d, lsum);
        d = q0.y - (bf2f(ahA[a][1]) + bf2f(alA[a][1])); lsum = fmaf(d, d, lsum);
        d = q0.z - (bf2f(ahA[a][2]) + bf2f(alA[a][2])); lsum = fmaf(d, d, lsum);
        d = q0.w - (bf2f(ahA[a][3]) + bf2f(alA[a][3])); lsum = fmaf(d, d, lsum);
        d = q1.x - (bf2f(ahA[a][4]) + bf2f(alA[a][4])); lsum = fmaf(d, d, lsum);
        d = q1.y - (bf2f(ahA[a][5]) + bf2f(alA[a][5])); lsum = fmaf(d, d, lsum);
        d = q1.z - (bf2f(ahA[a][6]) + bf2f(alA[a][6])); lsum = fmaf(d, d, lsum);
        d = q1.w - (bf2f(ahA[a][7]) + bf2f(alA[a][7])); lsum = fmaf(d, d, lsum);
        d = q2.x - (bf2f(ahB[a][0]) + bf2f(alB[a][0])); lsum = fmaf(d, d, lsum);
        d = q2.y - (bf2f(ahB[a][1]) + bf2f(alB[a][1])); lsum = fmaf(d, d, lsum);
        d = q2.z - (bf2f(ahB[a][2]) + bf2f(alB[a][2])); lsum = fmaf(d, d, lsum);
        d = q2.w - (bf2f(ahB[a][3]) + bf2f(alB[a][3])); lsum = fmaf(d, d, lsum);
        d = q3.x - (bf2f(ahB[a][4]) + bf2f(alB[a][4])); lsum = fmaf(d, d, lsum);
        d = q3.y - (bf2f(ahB[a][5]) + bf2f(alB[a][5])); lsum = fmaf(d, d, lsum);
        d = q3.z - (bf2f(ahB[a][6]) + bf2f(alB[a][6])); lsum = fmaf(d, d, lsum);
        d = q3.w - (bf2f(ahB[a][7]) + bf2f(alB[a][7])); lsum = fmaf(d, d, lsum);
    }

#pragma unroll
    for (int off = 32; off > 0; off >>= 1) lsum += __shfl_down(lsum, off);
    if (lane == 0) red[w] = lsum;
    __syncthreads();
    if (tid == 0) {
        float s = (red[0] + red[1]) + (red[2] + red[3]);
        atomicAdd(out + LOSS_OFF, s * (2.0f / (float)QOUT_SIZE));
    }
}

extern "C" void kernel_launch(void* const* d_in, const int* in_sizes, int n_in,
                              void* d_out, int out_size, void* d_ws, size_t ws_size,
                              hipStream_t stream) {
    const float* enc = (const float*)d_in[0];
    const float* embed = (const float*)d_in[1];
    float* out = (float*)d_out;
    // ws layout: ehi[512*64] u16 | elo[512*64] u16 | esq[512] f32  (~130 KB)
    unsigned short* ehi = (unsigned short*)d_ws;
    unsigned short* elo = ehi + KQ * DQ;
    float* esq = (float*)(elo + KQ * DQ);

    hipLaunchKernelGGL(vq_init_kernel, dim3(64), dim3(64), 0, stream,
                       embed, ehi, elo, esq, out);
    hipLaunchKernelGGL(vq_mfma_kernel, dim3(NBLK), dim3(256), 0, stream,
                       enc, embed, ehi, elo, esq, out);
}

// Round 13
// 141.779 us; speedup vs baseline: 1.6737x; 1.2054x over previous
//
#include <hip/hip_runtime.h>
#include <math.h>

// Problem constants (fixed by reference: enc (32,64,64,64) fp32, embed (512,64) fp32)
#define DQ 64
#define KQ 512
#define NVEC 131072
#define QOUT_SIZE (NVEC * DQ)              // 8388608
#define LOSS_OFF QOUT_SIZE
#define IDX_OFF (QOUT_SIZE + 1)

#define RPW 32                             // rows per wave (2 MFMA A-tiles)
#define WPB 4                              // waves per block (256 threads)
#define VPB (RPW * WPB)                    // 128 rows per block
#define NBLK (NVEC / VPB)                  // 1024 blocks -> 4 per CU
#define SC 64                              // codes per LDS stage
#define NST (KQ / SC)                      // 8 stages
#define SDQ (SC * DQ)                      // 4096 shorts per stage buffer
#define TIE_THR 0.01f                      // exact rescan when top-2 gap below this (err bound ~3e-4)

typedef __attribute__((ext_vector_type(8))) short short8;          // 8 bf16 = 1 MFMA A/B frag
typedef __attribute__((ext_vector_type(4))) float f32x4;           // MFMA C/D frag

static __device__ __forceinline__ unsigned short f2bf(float f) {   // RNE fp32->bf16
    unsigned u = __float_as_uint(f);
    u += 0x7fff + ((u >> 16) & 1);
    return (unsigned short)(u >> 16);
}
static __device__ __forceinline__ float bf2f(unsigned short h) {
    return __uint_as_float(((unsigned)h) << 16);
}
static __device__ __forceinline__ void cvt8(float4 a, float4 b, short8& hi, short8& lo) {
#define C1(I, V) { unsigned short _h = f2bf(V); hi[I] = (short)_h; lo[I] = (short)f2bf((V) - bf2f(_h)); }
    C1(0, a.x) C1(1, a.y) C1(2, a.z) C1(3, a.w)
    C1(4, b.x) C1(5, b.y) C1(6, b.z) C1(7, b.w)
#undef C1
}

// Init: hi/lo bf16 codebook in XOR-SWIZZLED layout (chunk c of row k stored at
// slot c ^ (k&7)) so main-kernel ds_read_b128 B-frag reads are 2-way max
// (free), while staging stays a verbatim contiguous copy. Plus e_sq + loss=0.
__global__ void vq_init_kernel(const float* __restrict__ embed,
                               unsigned short* __restrict__ ehi,
                               unsigned short* __restrict__ elo,
                               float* __restrict__ esq,
                               float* __restrict__ out) {
    const int t = blockIdx.x * 64 + threadIdx.x;   // 0..4095
    if (t == 0) out[LOSS_OFF] = 0.0f;
    const int k = t >> 3;            // codebook row
    const int c = t & 7;             // 16-byte chunk (8 dims)
    const float4* p = (const float4*)(embed + (size_t)k * DQ + c * 8);
    float4 a = p[0], b = p[1];
    short8 hi, lo;
    cvt8(a, b, hi, lo);
    const int slot = c ^ (k & 7);    // XOR swizzle
    *(short8*)(ehi + (size_t)k * DQ + slot * 8) = hi;
    *(short8*)(elo + (size_t)k * DQ + slot * 8) = lo;

    float ps = 0.f;
    ps = fmaf(a.x, a.x, ps); ps = fmaf(a.y, a.y, ps); ps = fmaf(a.z, a.z, ps); ps = fmaf(a.w, a.w, ps);
    ps = fmaf(b.x, b.x, ps); ps = fmaf(b.y, b.y, ps); ps = fmaf(b.z, b.z, ps); ps = fmaf(b.w, b.w, ps);
    ps += __shfl_xor(ps, 1);
    ps += __shfl_xor(ps, 2);
    ps += __shfl_xor(ps, 4);
    if (c == 0) esq[k] = ps;
}

// R12 CONFIRMED the allocator rule: VGPR budget = 512 / (provable max
// waves/SIMD), where provable-max = min(LDS WGs/CU, slot WGs/CU); attributes
// are ignored. R12 (55 KB LDS -> 2 WGs -> 256 budget) ran spill-free at 196
// VGPRs but was latency-bound at 2 waves/SIMD (all pipes <20%). This round:
// shrink per-wave state to a 128-reg budget and pin 4 waves/SIMD: RPW=32
// (2 A-tiles, demand ~120), LDS sized naturally ~35.3 KB -> floor(160/35.3)
// = 4 WGs/CU -> budget 512/4 = 128. 2x the wave interleave at zero spill.
// R6-R9 lesson: no global loads in the k-loop (LDS-staged codebook, dbuf,
// reg-prefetch two stages ahead). R3 lesson: VGPR arrays only indexed by
// fully-unrolled constants.
__global__ __launch_bounds__(256) void vq_mfma_kernel(const float* __restrict__ enc,
                                                      const float* __restrict__ embed,
                                                      const unsigned short* __restrict__ ehi,
                                                      const unsigned short* __restrict__ elo,
                                                      const float* __restrict__ esq,
                                                      float* __restrict__ out) {
    __shared__ unsigned short hs[2 * SDQ];     // hi stages (dbuf): 16 KB
    __shared__ unsigned short ls_[2 * SDQ];    // lo stages (dbuf): 16 KB
    __shared__ float esq_s[KQ];                // 2 KB
    __shared__ int bidx_s[VPB];                // 0.5 KB
    __shared__ int flag_s[VPB];                // 0.5 KB
    __shared__ float red[WPB];

    const int tid = threadIdx.x;
    const int lane = tid & 63;
    const int w = tid >> 6;            // wave 0..3
    const int l15 = lane & 15;
    const int l4 = lane >> 4;          // 0..3
    const int vb = blockIdx.x * VPB + w * RPW;

    esq_s[tid] = esq[tid];
    esq_s[tid + 256] = esq[tid + 256];

    // A fragments for 2 tiles: row m = l15 (+a*16), k-chunks l4*8 and 32+l4*8.
    short8 ahA[2], alA[2], ahB[2], alB[2];
#pragma unroll
    for (int a = 0; a < 2; a++) {
        const float* base = enc + (size_t)(vb + a * 16 + l15) * DQ + l4 * 8;
        const float4* p0 = (const float4*)base;
        const float4* p1 = (const float4*)(base + 32);
        cvt8(p0[0], p0[1], ahA[a], alA[a]);
        cvt8(p1[0], p1[1], ahB[a], alB[a]);
    }

    float m1[8], m2[8];
    int i1[8];
#pragma unroll
    for (int r = 0; r < 8; r++) { m1[r] = 3.4e38f; m2[r] = 3.4e38f; i1[r] = 0; }

    // Swizzled B-frag slot offsets (elements); key = l15&7.
    const int sl0 = (l4 ^ (l15 & 7)) * 8;    // chunk l4     (dims l4*8..+8)
    const int sl1 = sl0 ^ 32;                // chunk 4+l4   (dims 32+l4*8..+8)

    // Staging: thread stages 32 B hi + 32 B lo per stage (two b128 writes each;
    // consecutive 16B groups -> 2-way max = free).
    short8 rh0 = *(const short8*)(ehi + tid * 8);
    short8 rh1 = *(const short8*)(ehi + 2048 + tid * 8);
    short8 rl0 = *(const short8*)(elo + tid * 8);
    short8 rl1 = *(const short8*)(elo + 2048 + tid * 8);
    // write stage 0 into buf 0
    *(short8*)(hs + tid * 8) = rh0;  *(short8*)(hs + 2048 + tid * 8) = rh1;
    *(short8*)(ls_ + tid * 8) = rl0; *(short8*)(ls_ + 2048 + tid * 8) = rl1;
    // prefetch stage 1 into regs
    rh0 = *(const short8*)(ehi + SDQ + tid * 8);
    rh1 = *(const short8*)(ehi + SDQ + 2048 + tid * 8);
    rl0 = *(const short8*)(elo + SDQ + tid * 8);
    rl1 = *(const short8*)(elo + SDQ + 2048 + tid * 8);

#define LDB(H0, H1, L0, L1, S) { const int _o = ((S) * 16 + l15) * DQ; \
    H0 = *(const short8*)(hb + _o + sl0); H1 = *(const short8*)(hb + _o + sl1); \
    L0 = *(const short8*)(lb + _o + sl0); L1 = *(const short8*)(lb + _o + sl1); }

#define BODY(ST, S, BH0, BH1, BL0, BL1) { \
    const int code = (ST) * SC + (S) * 16 + l15; \
    const float ev = esq_s[code]; \
    _Pragma("unroll") \
    for (int a = 0; a < 2; a++) { \
        f32x4 acc = {0.f, 0.f, 0.f, 0.f}; \
        acc = __builtin_amdgcn_mfma_f32_16x16x32_bf16(ahA[a], BH0, acc, 0, 0, 0); \
        acc = __builtin_amdgcn_mfma_f32_16x16x32_bf16(ahB[a], BH1, acc, 0, 0, 0); \
        acc = __builtin_amdgcn_mfma_f32_16x16x32_bf16(alA[a], BH0, acc, 0, 0, 0); \
        acc = __builtin_amdgcn_mfma_f32_16x16x32_bf16(alB[a], BH1, acc, 0, 0, 0); \
        acc = __builtin_amdgcn_mfma_f32_16x16x32_bf16(ahA[a], BL0, acc, 0, 0, 0); \
        acc = __builtin_amdgcn_mfma_f32_16x16x32_bf16(ahB[a], BL1, acc, 0, 0, 0); \
        _Pragma("unroll") \
        for (int r = 0; r < 4; r++) { \
            float v = fmaf(-2.0f, acc[r], ev); \
            bool lt = v < m1[a * 4 + r]; \
            i1[a * 4 + r] = lt ? code : i1[a * 4 + r]; \
            m2[a * 4 + r] = fminf(m2[a * 4 + r], fmaxf(m1[a * 4 + r], v)); \
            m1[a * 4 + r] = fminf(m1[a * 4 + r], v); \
        } \
    } }

    for (int st = 0; st < NST; st++) {
        // Drains: LDS writes of buf[st&1] (done last iter) + global loads
        // issued last iter (they had a full stage of compute cover).
        __syncthreads();
        if (st < NST - 1) {                  // write stage st+1 into other buf
            unsigned short* hw = hs + ((st + 1) & 1) * SDQ;
            unsigned short* lw = ls_ + ((st + 1) & 1) * SDQ;
            *(short8*)(hw + tid * 8) = rh0;  *(short8*)(hw + 2048 + tid * 8) = rh1;
            *(short8*)(lw + tid * 8) = rl0;  *(short8*)(lw + 2048 + tid * 8) = rl1;
        }
        if (st < NST - 2) {                  // prefetch stage st+2 (overlaps compute)
            const int o = (st + 2) * SDQ;
            rh0 = *(const short8*)(ehi + o + tid * 8);
            rh1 = *(const short8*)(ehi + o + 2048 + tid * 8);
            rl0 = *(const short8*)(elo + o + tid * 8);
            rl1 = *(const short8*)(elo + o + 2048 + tid * 8);
        }
        const unsigned short* hb = hs + (st & 1) * SDQ;
        const unsigned short* lb = ls_ + (st & 1) * SDQ;
        // 4 tiles, even/odd B double-buffer in regs (pure LDS->MFMA->VALU)
        short8 b0h0, b0h1, b0l0, b0l1, b1h0, b1h1, b1l0, b1l1;
        LDB(b0h0, b0h1, b0l0, b0l1, 0)
        LDB(b1h0, b1h1, b1l0, b1l1, 1)
        BODY(st, 0, b0h0, b0h1, b0l0, b0l1)
        LDB(b0h0, b0h1, b0l0, b0l1, 2)
        BODY(st, 1, b1h0, b1h1, b1l0, b1l1)
        LDB(b1h0, b1h1, b1l0, b1l1, 3)
        BODY(st, 2, b0h0, b0h1, b0l0, b0l1)
        BODY(st, 3, b1h0, b1h1, b1l0, b1l1)
    }
#undef LDB
#undef BODY

    // Cross-lane merge over the 16 cols (xor on lane&15 bits).
#pragma unroll
    for (int m = 1; m <= 8; m <<= 1) {
#pragma unroll
        for (int r = 0; r < 8; r++) {
            float o1 = __shfl_xor(m1[r], m);
            float o2 = __shfl_xor(m2[r], m);
            int oi = __shfl_xor(i1[r], m);
            float nm2 = fminf(fminf(m2[r], o2), fmaxf(m1[r], o1));
            bool lt = o1 < m1[r];
            i1[r] = lt ? oi : i1[r];
            m1[r] = fminf(m1[r], o1);
            m2[r] = nm2;
        }
    }

    if (l15 == 0) {
#pragma unroll
        for (int a = 0; a < 2; a++)
#pragma unroll
            for (int r = 0; r < 4; r++) {
                const int row = a * 16 + l4 * 4 + r;
                bidx_s[w * RPW + row] = i1[a * 4 + r];
                flag_s[w * RPW + row] = (m2[a * 4 + r] - m1[a * 4 + r] < TIE_THR) ? 1 : 0;
            }
    }
    // bidx_s/flag_s are per-wave segments -> wave-internal visibility only.

    // Exact fp64 rescan of flagged rows (wave-uniform branch; rare ~1%).
    for (int row = 0; row < RPW; row++) {
        if (flag_s[w * RPW + row]) {
            const int v = vb + row;
            const float4* xe = (const float4*)(enc + (size_t)v * DQ);
            unsigned long long best = ~0ULL;
            for (int q = 0; q < 8; q++) {
                const int c = lane * 8 + q;
                const float4* ee = (const float4*)(embed + (size_t)c * DQ);
                double a = 0.0;
                for (int j = 0; j < 16; j++) {          // global ptrs: runtime j fine
                    float4 xx = xe[j], ez = ee[j];
                    double d0 = (double)xx.x - (double)ez.x; a = fma(d0, d0, a);
                    double d1 = (double)xx.y - (double)ez.y; a = fma(d1, d1, a);
                    double d2 = (double)xx.z - (double)ez.z; a = fma(d2, d2, a);
                    double d3 = (double)xx.w - (double)ez.w; a = fma(d3, d3, a);
                }
                unsigned long long p =
                    (((unsigned long long)__double_as_longlong(a)) & ~511ULL) | (unsigned)c;
                best = (p < best) ? p : best;
            }
#pragma unroll
            for (int mm = 1; mm < 64; mm <<= 1) {
                unsigned long long ob = (unsigned long long)__shfl_xor((long long)best, mm);
                best = (ob < best) ? ob : best;
            }
            if (lane == 0) bidx_s[w * RPW + row] = (int)(best & 511ULL);
        }
    }

    // Epilogue: per tile a, lane handles row a*16+l15, chunks l4*8 and 32+l4*8.
    // x recomputed from the hi/lo frags (≈1e-5 rel err; loss-only).
    float lsum = 0.f;
#pragma unroll
    for (int a = 0; a < 2; a++) {
        const int myv = vb + a * 16 + l15;
        const int qb = bidx_s[w * RPW + a * 16 + l15];
        const float* qbase = embed + (size_t)qb * DQ + l4 * 8;
        const float4* qa = (const float4*)qbase;
        const float4* qc = (const float4*)(qbase + 32);
        float4 q0 = qa[0], q1 = qa[1], q2 = qc[0], q3 = qc[1];
        float* obase = out + (size_t)myv * DQ + l4 * 8;
        ((float4*)obase)[0] = q0; ((float4*)obase)[1] = q1;
        ((float4*)(obase + 32))[0] = q2; ((float4*)(obase + 32))[1] = q3;
        if (l4 == 0) out[IDX_OFF + myv] = (float)qb;

        float d;
        d = q0.x - (bf2f(ahA[a][0]) + bf2f(alA[a][0])); lsum = fmaf(d, d, lsum);
        d = q0.y - (bf2f(ahA[a][1]) + bf2f(alA[a][1])); lsum = fmaf(d, d, lsum);
        d = q0.z - (bf2f(ahA[a][2]) + bf2f(alA[a][2])); lsum = fmaf(d, d, lsum);
        d = q0.w - (bf2f(ahA[a][3]) + bf2f(alA[a][3])); lsum = fmaf(d, d, lsum);
        d = q1.x - (bf2f(ahA[a][4]) + bf2f(alA[a][4])); lsum = fmaf(d, d, lsum);
        d = q1.y - (bf2f(ahA[a][5]) + bf2f(alA[a][5])); lsum = fmaf(d, d, lsum);
        d = q1.z - (bf2f(ahA[a][6]) + bf2f(alA[a][6])); lsum = fmaf(d, d, lsum);
        d = q1.w - (bf2f(ahA[a][7]) + bf2f(alA[a][7])); lsum = fmaf(d, d, lsum);
        d = q2.x - (bf2f(ahB[a][0]) + bf2f(alB[a][0])); lsum = fmaf(d, d, lsum);
        d = q2.y - (bf2f(ahB[a][1]) + bf2f(alB[a][1])); lsum = fmaf(d, d, lsum);
        d = q2.z - (bf2f(ahB[a][2]) + bf2f(alB[a][2])); lsum = fmaf(d, d, lsum);
        d = q2.w - (bf2f(ahB[a][3]) + bf2f(alB[a][3])); lsum = fmaf(d, d, lsum);
        d = q3.x - (bf2f(ahB[a][4]) + bf2f(alB[a][4])); lsum = fmaf(d, d, lsum);
        d = q3.y - (bf2f(ahB[a][5]) + bf2f(alB[a][5])); lsum = fmaf(d, d, lsum);
        d = q3.z - (bf2f(ahB[a][6]) + bf2f(alB[a][6])); lsum = fmaf(d, d, lsum);
        d = q3.w - (bf2f(ahB[a][7]) + bf2f(alB[a][7])); lsum = fmaf(d, d, lsum);
    }

#pragma unroll
    for (int off = 32; off > 0; off >>= 1) lsum += __shfl_down(lsum, off);
    if (lane == 0) red[w] = lsum;
    __syncthreads();
    if (tid == 0) {
        float s = (red[0] + red[1]) + (red[2] + red[3]);
        atomicAdd(out + LOSS_OFF, s * (2.0f / (float)QOUT_SIZE));
    }
}

extern "C" void kernel_launch(void* const* d_in, const int* in_sizes, int n_in,
                              void* d_out, int out_size, void* d_ws, size_t ws_size,
                              hipStream_t stream) {
    const float* enc = (const float*)d_in[0];
    const float* embed = (const float*)d_in[1];
    float* out = (float*)d_out;
    // ws layout: ehi[512*64] u16 | elo[512*64] u16 | esq[512] f32  (~130 KB)
    unsigned short* ehi = (unsigned short*)d_ws;
    unsigned short* elo = ehi + KQ * DQ;
    float* esq = (float*)(elo + KQ * DQ);

    hipLaunchKernelGGL(vq_init_kernel, dim3(64), dim3(64), 0, stream,
                       embed, ehi, elo, esq, out);
    hipLaunchKernelGGL(vq_mfma_kernel, dim3(NBLK), dim3(256), 0, stream,
                       enc, embed, ehi, elo, esq, out);
}